// Round 9
// baseline (184.710 us; speedup 1.0000x reference)
//
#include <hip/hip_runtime.h>
#include <hip/hip_bf16.h>

#define B_TOT   4096
#define T_STEPS 256
#define IN_D    28
#define HID     128
#define OUT_D   784
#define BM      16

typedef __bf16 bf16x8 __attribute__((ext_vector_type(8)));
typedef __bf16 bf16x4 __attribute__((ext_vector_type(4)));
typedef float  f32x4  __attribute__((ext_vector_type(4)));

__device__ __forceinline__ float bf2f(__bf16 b) {
    unsigned short s = __builtin_bit_cast(unsigned short, b);
    unsigned int u = ((unsigned int)s) << 16;
    return __builtin_bit_cast(float, u);
}

// H LDS layout: [16 rows b][128 bf16 n] = 256 B/row, XOR-swizzled (verified r7/r8).
__device__ __forceinline__ int hswz(int row, int byteInRow) {
    return row * 256 + (byteInRow ^ ((row & 7) << 4));
}

// ONE WAVE per block: 16 batch rows, full 128-wide hidden state.
// Recurrence is entirely intra-wave: weights register-resident, h relayout
// (D-layout -> B-operand layout) through wave-private LDS with only the
// hardware's in-order per-wave LDS pipeline + compiler lgkmcnt. NO barriers.
__global__ __launch_bounds__(64, 1) void rnn_fused(
    const float* __restrict__ x,     // [B,T,IN] f32
    const float* __restrict__ h0,    // [B,HID] f32
    const float* __restrict__ W_ih,  // [HID,IN] f32
    const float* __restrict__ b_ih,  // [HID] f32
    const float* __restrict__ W_hh,  // [HID,HID] f32
    const float* __restrict__ b_hh,  // [HID] f32
    const float* __restrict__ W_ho,  // [OUT_D,HID] f32
    const float* __restrict__ b_ho,  // [OUT_D] f32
    float* __restrict__ out)         // [B*OUT_D] f32, then [B*HID] f32
{
    __shared__ __align__(16) unsigned char Hb[2][BM * 256]; // h (bf16) double buffer

    const int lane = threadIdx.x & 63;
    const int ln15 = lane & 15;
    const int lg   = lane >> 4;      // k-group / col-group 0..3
    const int b0   = blockIdx.x * BM;

    // ---- ALL weight fragments register-resident (A-operand: A[m=n_out][k],
    // lane: m = q*16 + ln15, k = 8*lg + e). 8 n-tiles x 4 k-chunks.
    bf16x8 bw[8][4];
    #pragma unroll
    for (int q = 0; q < 8; ++q) {
        int n = q * 16 + ln15;
        #pragma unroll
        for (int kc = 0; kc < 4; ++kc) {
            const float* p = W_hh + n * HID + kc * 32 + lg * 8;
            bf16x8 v;
            #pragma unroll
            for (int e = 0; e < 8; ++e) v[e] = (__bf16)p[e];
            bw[q][kc] = v;
        }
    }
    const __bf16 bzero = (__bf16)0.0f;
    bf16x8 bxf[8];
    #pragma unroll
    for (int q = 0; q < 8; ++q) {
        int n = q * 16 + ln15;
        bf16x8 v;
        #pragma unroll
        for (int e = 0; e < 8; ++e) {
            int k = lg * 8 + e;
            v[e] = (k < IN_D) ? (__bf16)W_ih[n * IN_D + k] : bzero;  // zero-pad K 28->32
        }
        bxf[q] = v;
    }
    // bias per lane: D row = n_out = q*16 + 4*lg + r (4 consecutive)
    f32x4 bias4[8];
    #pragma unroll
    for (int q = 0; q < 8; ++q) {
        int n = q * 16 + 4 * lg;
        f32x4 bi = *(const f32x4*)(b_ih + n);
        f32x4 bh = *(const f32x4*)(b_hh + n);
        bias4[q] = bi + bh;
    }

    // ---- stage initial hidden into Hb[0] (f32 -> bf16); same wave, no barrier
    #pragma unroll
    for (int rep = 0; rep < 4; ++rep) {
        int row = rep * 4 + lg, cg = ln15;
        const float* p = h0 + (size_t)(b0 + row) * HID + cg * 8;
        bf16x8 hv;
        #pragma unroll
        for (int e = 0; e < 8; ++e) hv[e] = (__bf16)p[e];
        *(bf16x8*)(&Hb[0][hswz(row, cg * 16)]) = hv;
    }

    // ---- per-lane x fragments (verified r8): lane owns row b0+ln15, k-chunk lg.
    // lg=3 upper half clamped (k=28..31 dead via zero-padded W_ih frag).
    const float* xlane  = x + (size_t)(b0 + ln15) * T_STEPS * IN_D + lg * 8;
    const float* xlane2 = x + (size_t)(b0 + ln15) * T_STEPS * IN_D + (lg == 3 ? 24 : lg * 8 + 4);
    // register ring, depth 4 (statically indexed)
    f32x4 q0a = *(const f32x4*)(xlane  + 0 * IN_D), q0b = *(const f32x4*)(xlane2 + 0 * IN_D);
    f32x4 q1a = *(const f32x4*)(xlane  + 1 * IN_D), q1b = *(const f32x4*)(xlane2 + 1 * IN_D);
    f32x4 q2a = *(const f32x4*)(xlane  + 2 * IN_D), q2b = *(const f32x4*)(xlane2 + 2 * IN_D);
    f32x4 q3a = *(const f32x4*)(xlane  + 3 * IN_D), q3b = *(const f32x4*)(xlane2 + 3 * IN_D);

    // ================= recurrence: 256 steps, ZERO barriers =================
    // Transposed MFMA: D[n_out][batch] = W * h^T. A = weight frags (regs),
    // B = h frags (4x ds_read_b128 from wave-private LDS) / x frag (regs).
    // x-MFMAs issued first (independent of h) to hide the LDS read latency.
#define STEP(T, QA, QB)                                                         \
    {                                                                           \
        const int rb = (T) & 1;                                                 \
        bf16x8 ah0 = *(const bf16x8*)(&Hb[rb][hswz(ln15,   0 + lg * 16)]);      \
        bf16x8 ah1 = *(const bf16x8*)(&Hb[rb][hswz(ln15,  64 + lg * 16)]);      \
        bf16x8 ah2 = *(const bf16x8*)(&Hb[rb][hswz(ln15, 128 + lg * 16)]);      \
        bf16x8 ah3 = *(const bf16x8*)(&Hb[rb][hswz(ln15, 192 + lg * 16)]);      \
        bf16x8 ax;                                                              \
        _Pragma("unroll")                                                       \
        for (int e = 0; e < 4; ++e) { ax[e] = (__bf16)QA[e]; ax[4 + e] = (__bf16)QB[e]; } \
        f32x4 acc[8];                                                           \
        _Pragma("unroll")                                                       \
        for (int q = 0; q < 8; ++q)                                             \
            acc[q] = __builtin_amdgcn_mfma_f32_16x16x32_bf16(bxf[q], ax, bias4[q], 0, 0, 0); \
        if ((T) + 4 < T_STEPS) {                                                \
            QA = *(const f32x4*)(xlane  + (size_t)((T) + 4) * IN_D);            \
            QB = *(const f32x4*)(xlane2 + (size_t)((T) + 4) * IN_D);            \
        }                                                                       \
        _Pragma("unroll")                                                       \
        for (int q = 0; q < 8; ++q)                                             \
            acc[q] = __builtin_amdgcn_mfma_f32_16x16x32_bf16(bw[q][0], ah0, acc[q], 0, 0, 0); \
        _Pragma("unroll")                                                       \
        for (int q = 0; q < 8; ++q)                                             \
            acc[q] = __builtin_amdgcn_mfma_f32_16x16x32_bf16(bw[q][1], ah1, acc[q], 0, 0, 0); \
        _Pragma("unroll")                                                       \
        for (int q = 0; q < 8; ++q)                                             \
            acc[q] = __builtin_amdgcn_mfma_f32_16x16x32_bf16(bw[q][2], ah2, acc[q], 0, 0, 0); \
        _Pragma("unroll")                                                       \
        for (int q = 0; q < 8; ++q)                                             \
            acc[q] = __builtin_amdgcn_mfma_f32_16x16x32_bf16(bw[q][3], ah3, acc[q], 0, 0, 0); \
        _Pragma("unroll")                                                       \
        for (int q = 0; q < 8; ++q) {                                           \
            bf16x4 w;                                                           \
            _Pragma("unroll")                                                   \
            for (int r = 0; r < 4; ++r) {                                       \
                float v = acc[q][r];                                            \
                w[r] = (__bf16)(v > 0.f ? v : 0.f);                             \
            }                                                                   \
            *(bf16x4*)(&Hb[rb ^ 1][hswz(ln15, q * 32 + lg * 8)]) = w;           \
        }                                                                       \
    }

    for (int t = 0; t < T_STEPS; t += 4) {
        STEP(t + 0, q0a, q0b)
        STEP(t + 1, q1a, q1b)
        STEP(t + 2, q2a, q2b)
        STEP(t + 3, q3a, q3b)
    }
#undef STEP
    // after t=255 (rb=1) the final h sits in Hb[0]

    // ================= epilogue (single wave) =================
    // h_final -> d_out second segment (f32)
    #pragma unroll
    for (int rep = 0; rep < 4; ++rep) {
        int row = rep * 4 + lg, cg = ln15;
        bf16x8 hv = *(const bf16x8*)(&Hb[0][hswz(row, cg * 16)]);
        float* po = out + (size_t)B_TOT * OUT_D + (size_t)(b0 + row) * HID + cg * 8;
        #pragma unroll
        for (int e = 0; e < 8; ++e) po[e] = bf2f(hv[e]);
    }
    // projection (transposed form): D[o][batch], A = W_ho frag, B = h frag.
    bf16x8 af[4];
    #pragma unroll
    for (int kc = 0; kc < 4; ++kc)
        af[kc] = *(const bf16x8*)(&Hb[0][hswz(ln15, kc * 64 + lg * 16)]);

    for (int nt = 0; nt < 49; ++nt) {
        f32x4 acc = *(const f32x4*)(b_ho + nt * 16 + 4 * lg);
        #pragma unroll
        for (int kc = 0; kc < 4; ++kc) {
            const float* p = W_ho + (nt * 16 + ln15) * HID + kc * 32 + lg * 8;
            bf16x8 bfrag;
            #pragma unroll
            for (int e = 0; e < 8; ++e) bfrag[e] = (__bf16)p[e];
            acc = __builtin_amdgcn_mfma_f32_16x16x32_bf16(bfrag, af[kc], acc, 0, 0, 0);
        }
        // lane holds batch=ln15, o = nt*16 + 4lg + r -> one dwordx4 store
        *(f32x4*)(out + (size_t)(b0 + ln15) * OUT_D + nt * 16 + 4 * lg) = acc;
    }
}

extern "C" void kernel_launch(void* const* d_in, const int* in_sizes, int n_in,
                              void* d_out, int out_size, void* d_ws, size_t ws_size,
                              hipStream_t stream) {
    const float* x    = (const float*)d_in[0];
    const float* h0   = (const float*)d_in[1];
    const float* W_ih = (const float*)d_in[2];
    const float* b_ih = (const float*)d_in[3];
    const float* W_hh = (const float*)d_in[4];
    const float* b_hh = (const float*)d_in[5];
    const float* W_ho = (const float*)d_in[6];
    const float* b_ho = (const float*)d_in[7];
    rnn_fused<<<B_TOT / BM, 64, 0, stream>>>(x, h0, W_ih, b_ih, W_hh, b_hh,
                                             W_ho, b_ho, (float*)d_out);
}

// Round 10
// 123.160 us; speedup vs baseline: 1.4998x; 1.4998x over previous
//
#include <hip/hip_runtime.h>
#include <hip/hip_bf16.h>

#define B_TOT   4096
#define T_STEPS 256
#define IN_D    28
#define HID     128
#define OUT_D   784
#define BM      16

typedef __bf16 bf16x8 __attribute__((ext_vector_type(8)));
typedef __bf16 bf16x4 __attribute__((ext_vector_type(4)));
typedef float  f32x4  __attribute__((ext_vector_type(4)));

__device__ __forceinline__ float bf2f(__bf16 b) {
    unsigned short s = __builtin_bit_cast(unsigned short, b);
    unsigned int u = ((unsigned int)s) << 16;
    return __builtin_bit_cast(float, u);
}

// H LDS layout: [16 rows b][128 bf16 n] = 256 B/row, XOR-swizzled (verified r7/r8).
__device__ __forceinline__ int hswz(int row, int byteInRow) {
    return row * 256 + (byteInRow ^ ((row & 7) << 4));
}

__global__ __launch_bounds__(256) void rnn_fused(
    const float* __restrict__ x,     // [B,T,IN] f32
    const float* __restrict__ h0,    // [B,HID] f32
    const float* __restrict__ W_ih,  // [HID,IN] f32
    const float* __restrict__ b_ih,  // [HID] f32
    const float* __restrict__ W_hh,  // [HID,HID] f32
    const float* __restrict__ b_hh,  // [HID] f32
    const float* __restrict__ W_ho,  // [OUT_D,HID] f32
    const float* __restrict__ b_ho,  // [OUT_D] f32
    float* __restrict__ out)         // [B*OUT_D] f32, then [B*HID] f32
{
    __shared__ __align__(16) unsigned char Hb[2][BM * 256]; // h (bf16) double buffer

    const int tid  = threadIdx.x;
    const int lane = tid & 63;
    const int wv   = tid >> 6;       // wave 0..3
    const int ln15 = lane & 15;
    const int lg   = lane >> 4;      // k-group 0..3
    const int b0   = blockIdx.x * BM;

    // ---- Weight fragments (f32 -> bf16), register-resident, MFMA *A* operand:
    // A[m = n_out][k], lane: m = nt + ln15, k = 8*lg + e.  (verified r7)
    const int nt0 = wv * 32;         // this wave owns hidden cols [nt0, nt0+32)
    bf16x8 bw[2][4];
    #pragma unroll
    for (int ti = 0; ti < 2; ++ti) {
        int n = nt0 + ti * 16 + ln15;
        #pragma unroll
        for (int kc = 0; kc < 4; ++kc) {
            const float* p = W_hh + n * HID + kc * 32 + lg * 8;
            bf16x8 v;
            #pragma unroll
            for (int e = 0; e < 8; ++e) v[e] = (__bf16)p[e];
            bw[ti][kc] = v;
        }
    }
    const __bf16 bzero = (__bf16)0.0f;
    bf16x8 bxf[2];
    #pragma unroll
    for (int ti = 0; ti < 2; ++ti) {
        int n = nt0 + ti * 16 + ln15;
        bf16x8 v;
        #pragma unroll
        for (int e = 0; e < 8; ++e) {
            int k = lg * 8 + e;
            v[e] = (k < IN_D) ? (__bf16)W_ih[n * IN_D + k] : bzero;  // zero-pad K 28->32
        }
        bxf[ti] = v;
    }
    // bias per lane: D row = n_out = nt0 + ti*16 + 4*lg + r  (4 consecutive)
    f32x4 bias4[2];
    #pragma unroll
    for (int ti = 0; ti < 2; ++ti) {
        int n = nt0 + ti * 16 + 4 * lg;
        f32x4 bi = *(const f32x4*)(b_ih + n);
        f32x4 bh = *(const f32x4*)(b_hh + n);
        bias4[ti] = bi + bh;
    }

    // ---- stage initial hidden into Hb[0] (f32 -> bf16)
    {
        int row = tid >> 4, cg = tid & 15;
        const float* p = h0 + (size_t)(b0 + row) * HID + cg * 8;
        bf16x8 hv;
        #pragma unroll
        for (int e = 0; e < 8; ++e) hv[e] = (__bf16)p[e];
        *(bf16x8*)(&Hb[0][hswz(row, cg * 16)]) = hv;
    }

    // ---- per-lane x fragments (verified r8/r9): lane owns batch row b0+ln15,
    // k-chunk lg. lg=3 upper half clamped (k=28..31 dead via zero-padded bxf).
    const float* xlane  = x + (size_t)(b0 + ln15) * T_STEPS * IN_D + lg * 8;
    const float* xlane2 = x + (size_t)(b0 + ln15) * T_STEPS * IN_D + (lg == 3 ? 24 : lg * 8 + 4);
    // register ring, depth 8, two groups of 4; reload ONE group per 4 steps so
    // 3 of 4 __syncthreads barriers have no VMEM in flight to drain.
    f32x4 xA0a = *(const f32x4*)(xlane + 0 * IN_D), xA0b = *(const f32x4*)(xlane2 + 0 * IN_D);
    f32x4 xA1a = *(const f32x4*)(xlane + 1 * IN_D), xA1b = *(const f32x4*)(xlane2 + 1 * IN_D);
    f32x4 xA2a = *(const f32x4*)(xlane + 2 * IN_D), xA2b = *(const f32x4*)(xlane2 + 2 * IN_D);
    f32x4 xA3a = *(const f32x4*)(xlane + 3 * IN_D), xA3b = *(const f32x4*)(xlane2 + 3 * IN_D);
    f32x4 zz = {0.f, 0.f, 0.f, 0.f};
    f32x4 xB0a = zz, xB0b = zz, xB1a = zz, xB1b = zz;
    f32x4 xB2a = zz, xB2b = zz, xB3a = zz, xB3b = zz;

    __syncthreads();

    // ================= recurrence: 256 steps, 1 barrier/step =================
    // Transposed MFMA (verified r7): D[n_out][batch] = W * h^T. A = weight
    // frags (regs), B = h frags (4x ds_read_b128) / x frag (regs). Lane holds
    // batch=ln15, n_out = nt0 + ti*16 + 4lg + r -> one ds_write_b64 per ti.
    // __VA_ARGS__ = optional x reload clause (8 global loads, once per 4 steps).
#define STEP(T, QA, QB, ...)                                                    \
    {                                                                           \
        const int rb = (T) & 1;                                                 \
        bf16x8 ah0 = *(const bf16x8*)(&Hb[rb][hswz(ln15,   0 + lg * 16)]);      \
        bf16x8 ah1 = *(const bf16x8*)(&Hb[rb][hswz(ln15,  64 + lg * 16)]);      \
        bf16x8 ah2 = *(const bf16x8*)(&Hb[rb][hswz(ln15, 128 + lg * 16)]);      \
        bf16x8 ah3 = *(const bf16x8*)(&Hb[rb][hswz(ln15, 192 + lg * 16)]);      \
        bf16x8 ax;                                                              \
        _Pragma("unroll")                                                       \
        for (int e = 0; e < 4; ++e) { ax[e] = (__bf16)QA[e]; ax[4 + e] = (__bf16)QB[e]; } \
        f32x4 a0 = __builtin_amdgcn_mfma_f32_16x16x32_bf16(bxf[0], ax, bias4[0], 0, 0, 0); \
        f32x4 a1 = __builtin_amdgcn_mfma_f32_16x16x32_bf16(bxf[1], ax, bias4[1], 0, 0, 0); \
        __VA_ARGS__                                                             \
        a0 = __builtin_amdgcn_mfma_f32_16x16x32_bf16(bw[0][0], ah0, a0, 0, 0, 0); \
        a1 = __builtin_amdgcn_mfma_f32_16x16x32_bf16(bw[1][0], ah0, a1, 0, 0, 0); \
        f32x4 c0 = __builtin_amdgcn_mfma_f32_16x16x32_bf16(bw[0][1], ah1, zz, 0, 0, 0); \
        f32x4 c1 = __builtin_amdgcn_mfma_f32_16x16x32_bf16(bw[1][1], ah1, zz, 0, 0, 0); \
        a0 = __builtin_amdgcn_mfma_f32_16x16x32_bf16(bw[0][2], ah2, a0, 0, 0, 0); \
        a1 = __builtin_amdgcn_mfma_f32_16x16x32_bf16(bw[1][2], ah2, a1, 0, 0, 0); \
        c0 = __builtin_amdgcn_mfma_f32_16x16x32_bf16(bw[0][3], ah3, c0, 0, 0, 0); \
        c1 = __builtin_amdgcn_mfma_f32_16x16x32_bf16(bw[1][3], ah3, c1, 0, 0, 0); \
        _Pragma("unroll")                                                       \
        for (int ti = 0; ti < 2; ++ti) {                                        \
            f32x4 s = ti ? (a1 + c1) : (a0 + c0);                               \
            bf16x4 w;                                                           \
            _Pragma("unroll")                                                   \
            for (int r = 0; r < 4; ++r) {                                       \
                float v = s[r];                                                 \
                w[r] = (__bf16)(v > 0.f ? v : 0.f);                             \
            }                                                                   \
            *(bf16x4*)(&Hb[rb ^ 1][hswz(ln15, nt0 * 2 + ti * 32 + lg * 8)]) = w; \
        }                                                                       \
        __syncthreads();                                                        \
    }

    for (int t = 0; t < T_STEPS; t += 8) {
        // invariant at body top: A = x_{t..t+3}, (B dead)
        STEP(t + 0, xA0a, xA0b,
            if (t + 4 < T_STEPS) {
                xB0a = *(const f32x4*)(xlane  + (size_t)(t + 4) * IN_D);
                xB0b = *(const f32x4*)(xlane2 + (size_t)(t + 4) * IN_D);
                xB1a = *(const f32x4*)(xlane  + (size_t)(t + 5) * IN_D);
                xB1b = *(const f32x4*)(xlane2 + (size_t)(t + 5) * IN_D);
                xB2a = *(const f32x4*)(xlane  + (size_t)(t + 6) * IN_D);
                xB2b = *(const f32x4*)(xlane2 + (size_t)(t + 6) * IN_D);
                xB3a = *(const f32x4*)(xlane  + (size_t)(t + 7) * IN_D);
                xB3b = *(const f32x4*)(xlane2 + (size_t)(t + 7) * IN_D);
            })
        STEP(t + 1, xA1a, xA1b, )
        STEP(t + 2, xA2a, xA2b, )
        STEP(t + 3, xA3a, xA3b, )
        STEP(t + 4, xB0a, xB0b,
            if (t + 8 < T_STEPS) {
                xA0a = *(const f32x4*)(xlane  + (size_t)(t + 8) * IN_D);
                xA0b = *(const f32x4*)(xlane2 + (size_t)(t + 8) * IN_D);
                xA1a = *(const f32x4*)(xlane  + (size_t)(t + 9) * IN_D);
                xA1b = *(const f32x4*)(xlane2 + (size_t)(t + 9) * IN_D);
                xA2a = *(const f32x4*)(xlane  + (size_t)(t + 10) * IN_D);
                xA2b = *(const f32x4*)(xlane2 + (size_t)(t + 10) * IN_D);
                xA3a = *(const f32x4*)(xlane  + (size_t)(t + 11) * IN_D);
                xA3b = *(const f32x4*)(xlane2 + (size_t)(t + 11) * IN_D);
            })
        STEP(t + 5, xB1a, xB1b, )
        STEP(t + 6, xB2a, xB2b, )
        STEP(t + 7, xB3a, xB3b, )
    }
#undef STEP
    // after t=255 (rb=1) the final h sits in Hb[0]; loop's last barrier done

    // ================= epilogue (verified r7) =================
    // h_final -> d_out second segment (f32)
    {
        int row = tid >> 4, cg = tid & 15;
        bf16x8 hv = *(const bf16x8*)(&Hb[0][hswz(row, cg * 16)]);
        float* po = out + (size_t)B_TOT * OUT_D + (size_t)(b0 + row) * HID + cg * 8;
        #pragma unroll
        for (int e = 0; e < 8; ++e) po[e] = bf2f(hv[e]);
    }
    // projection (transposed form): D[o][batch], A = W_ho frag, B = h frag.
    bf16x8 af[4];
    #pragma unroll
    for (int kc = 0; kc < 4; ++kc)
        af[kc] = *(const bf16x8*)(&Hb[0][hswz(ln15, kc * 64 + lg * 16)]);

    for (int nt = wv; nt < 49; nt += 4) {
        f32x4 acc = *(const f32x4*)(b_ho + nt * 16 + 4 * lg);
        #pragma unroll
        for (int kc = 0; kc < 4; ++kc) {
            const float* p = W_ho + (nt * 16 + ln15) * HID + kc * 32 + lg * 8;
            bf16x8 bfrag;
            #pragma unroll
            for (int e = 0; e < 8; ++e) bfrag[e] = (__bf16)p[e];
            acc = __builtin_amdgcn_mfma_f32_16x16x32_bf16(bfrag, af[kc], acc, 0, 0, 0);
        }
        // lane holds batch=ln15, o = nt*16 + 4lg + r -> one dwordx4 store
        *(f32x4*)(out + (size_t)(b0 + ln15) * OUT_D + nt * 16 + 4 * lg) = acc;
    }
}

extern "C" void kernel_launch(void* const* d_in, const int* in_sizes, int n_in,
                              void* d_out, int out_size, void* d_ws, size_t ws_size,
                              hipStream_t stream) {
    const float* x    = (const float*)d_in[0];
    const float* h0   = (const float*)d_in[1];
    const float* W_ih = (const float*)d_in[2];
    const float* b_ih = (const float*)d_in[3];
    const float* W_hh = (const float*)d_in[4];
    const float* b_hh = (const float*)d_in[5];
    const float* W_ho = (const float*)d_in[6];
    const float* b_ho = (const float*)d_in[7];
    rnn_fused<<<B_TOT / BM, 256, 0, stream>>>(x, h0, W_ih, b_ih, W_hh, b_hh,
                                              W_ho, b_ho, (float*)d_out);
}

// Round 12
// 104.551 us; speedup vs baseline: 1.7667x; 1.1780x over previous
//
#include <hip/hip_runtime.h>
#include <hip/hip_bf16.h>

#define B_TOT   4096
#define T_STEPS 256
#define IN_D    28
#define HID     128
#define OUT_D   784
#define BM      16

typedef __bf16 bf16x8 __attribute__((ext_vector_type(8)));
typedef __bf16 bf16x4 __attribute__((ext_vector_type(4)));
typedef float  f32x4  __attribute__((ext_vector_type(4)));
typedef float  f32x2  __attribute__((ext_vector_type(2)));

__device__ __forceinline__ float bf2f(__bf16 b) {
    unsigned short s = __builtin_bit_cast(unsigned short, b);
    unsigned int u = ((unsigned int)s) << 16;
    return __builtin_bit_cast(float, u);
}
__device__ __forceinline__ unsigned short f2bfbits(float f) {
    unsigned int u = __builtin_bit_cast(unsigned int, f);
    u += 0x7fffu + ((u >> 16) & 1u);   // RNE (finite values)
    return (unsigned short)(u >> 16);
}

// H LDS layout: [16 rows b][128 bf16 n] = 256 B/row, XOR-swizzled (verified r7).
__device__ __forceinline__ int hswz(int row, int byteInRow) {
    return row * 256 + (byteInRow ^ ((row & 7) << 4));
}

__global__ __launch_bounds__(256) void rnn_fused(
    const float* __restrict__ x,     // [B,T,IN] f32
    const float* __restrict__ h0,    // [B,HID] f32
    const float* __restrict__ W_ih,  // [HID,IN] f32
    const float* __restrict__ b_ih,  // [HID] f32
    const float* __restrict__ W_hh,  // [HID,HID] f32
    const float* __restrict__ b_hh,  // [HID] f32
    const float* __restrict__ W_ho,  // [OUT_D,HID] f32
    const float* __restrict__ b_ho,  // [OUT_D] f32
    float* __restrict__ out)         // [B*OUT_D] f32, then [B*HID] f32
{
    __shared__ __align__(16) unsigned char Hb[2][BM * 256]; // h (bf16) double buffer
    __shared__ __align__(16) unsigned char Xs[8 * 1024];    // x ring: 8 slots x [16 rows][64B]

    const int tid  = threadIdx.x;
    const int lane = tid & 63;
    const int wv   = tid >> 6;       // wave 0..3
    const int ln15 = lane & 15;
    const int lg   = lane >> 4;      // k-group 0..3
    const int b0   = blockIdx.x * BM;

    // ---- Weight fragments (f32 -> bf16), register-resident, MFMA *A* operand:
    // A[m = n_out][k], lane: m = nt + ln15, k = 8*lg + e.  (verified r7)
    const int nt0 = wv * 32;         // this wave owns hidden cols [nt0, nt0+32)
    bf16x8 bw[2][4];
    #pragma unroll
    for (int ti = 0; ti < 2; ++ti) {
        int n = nt0 + ti * 16 + ln15;
        #pragma unroll
        for (int kc = 0; kc < 4; ++kc) {
            const float* p = W_hh + n * HID + kc * 32 + lg * 8;
            bf16x8 v;
            #pragma unroll
            for (int e = 0; e < 8; ++e) v[e] = (__bf16)p[e];
            bw[ti][kc] = v;
        }
    }
    const __bf16 bzero = (__bf16)0.0f;
    bf16x8 bxf[2];
    #pragma unroll
    for (int ti = 0; ti < 2; ++ti) {
        int n = nt0 + ti * 16 + ln15;
        bf16x8 v;
        #pragma unroll
        for (int e = 0; e < 8; ++e) {
            int k = lg * 8 + e;
            v[e] = (k < IN_D) ? (__bf16)W_ih[n * IN_D + k] : bzero;  // zero-pad K 28->32
        }
        bxf[ti] = v;
    }
    // bias per lane: D row = n_out = nt0 + ti*16 + 4*lg + r  (4 consecutive)
    f32x4 bias4[2];
    #pragma unroll
    for (int ti = 0; ti < 2; ++ti) {
        int n = nt0 + ti * 16 + 4 * lg;
        f32x4 bi = *(const f32x4*)(b_ih + n);
        f32x4 bh = *(const f32x4*)(b_hh + n);
        bias4[ti] = bi + bh;
    }

    // ---- stage initial hidden into Hb[0] (f32 -> bf16)
    {
        int row = tid >> 4, cg = tid & 15;
        const float* p = h0 + (size_t)(b0 + row) * HID + cg * 8;
        bf16x8 hv;
        #pragma unroll
        for (int e = 0; e < 8; ++e) hv[e] = (__bf16)p[e];
        *(bf16x8*)(&Hb[0][hswz(row, cg * 16)]) = hv;
    }
    // ---- zero the k=28..31 pad of all 8 X ring slots (never rewritten)
    {
        int slot = tid >> 5, idx = tid & 31, row = idx >> 1, d = idx & 1;
        *(unsigned int*)(&Xs[slot * 1024 + row * 64 + 56 + d * 4]) = 0u;
    }
    // ---- x staging geometry (verified r7): 224 threads, 16 rows x 14 dword-pairs
    const int xrow = tid / 14, xpair = tid % 14;
    const bool xthr = (tid < 224);
    const float* xbase = x + (size_t)(b0 + xrow) * T_STEPS * IN_D + xpair * 2;
    // ---- pre-stage steps 0..3 into slots 0..3
    if (xthr) {
        #pragma unroll
        for (int s = 0; s < 4; ++s) {
            f32x2 v = *(const f32x2*)(xbase + (size_t)s * IN_D);
            unsigned int pk = ((unsigned int)f2bfbits(v[1]) << 16) | f2bfbits(v[0]);
            *(unsigned int*)(&Xs[s * 1024 + xrow * 64 + xpair * 4]) = pk;
        }
    }
    f32x2 sx0 = {0.f, 0.f}, sx1 = sx0, sx2 = sx0, sx3 = sx0;
    __syncthreads();

    // ================= recurrence: 256 steps, 1 barrier/step =================
    // Consume path identical to r7 (verified): transposed MFMA, A = weight
    // frags (regs), B = h frags (4x ds_read_b128) + x frag (1x ds_read_b128,
    // prepacked bf16). Lane holds batch=ln15, n_out = nt0+ti*16+4lg+r.
    // Stage clause (T%4==0): loads for steps T+4..T+7 issued FIRST (window =
    // full step to this step's barrier); pack+write to ring slots at step end.
    // Slot being read (T&7) is disjoint from slots written ((T+4..T+7)&7);
    // written slots are first read at step T+4 (>=1 barrier after the write).
#define STEP(T, STGL, STGW)                                                     \
    {                                                                           \
        const int rb = (T) & 1;                                                 \
        STGL                                                                    \
        bf16x8 ax  = *(const bf16x8*)(&Xs[((T) & 7) * 1024 + ln15 * 64 + lg * 16]); \
        bf16x8 ah0 = *(const bf16x8*)(&Hb[rb][hswz(ln15,   0 + lg * 16)]);      \
        bf16x8 ah1 = *(const bf16x8*)(&Hb[rb][hswz(ln15,  64 + lg * 16)]);      \
        bf16x8 ah2 = *(const bf16x8*)(&Hb[rb][hswz(ln15, 128 + lg * 16)]);      \
        bf16x8 ah3 = *(const bf16x8*)(&Hb[rb][hswz(ln15, 192 + lg * 16)]);      \
        f32x4 a0 = __builtin_amdgcn_mfma_f32_16x16x32_bf16(bxf[0], ax, bias4[0], 0, 0, 0); \
        f32x4 a1 = __builtin_amdgcn_mfma_f32_16x16x32_bf16(bxf[1], ax, bias4[1], 0, 0, 0); \
        f32x4 zz = {0.f, 0.f, 0.f, 0.f};                                        \
        a0 = __builtin_amdgcn_mfma_f32_16x16x32_bf16(bw[0][0], ah0, a0, 0, 0, 0); \
        a1 = __builtin_amdgcn_mfma_f32_16x16x32_bf16(bw[1][0], ah0, a1, 0, 0, 0); \
        f32x4 c0 = __builtin_amdgcn_mfma_f32_16x16x32_bf16(bw[0][1], ah1, zz, 0, 0, 0); \
        f32x4 c1 = __builtin_amdgcn_mfma_f32_16x16x32_bf16(bw[1][1], ah1, zz, 0, 0, 0); \
        a0 = __builtin_amdgcn_mfma_f32_16x16x32_bf16(bw[0][2], ah2, a0, 0, 0, 0); \
        a1 = __builtin_amdgcn_mfma_f32_16x16x32_bf16(bw[1][2], ah2, a1, 0, 0, 0); \
        c0 = __builtin_amdgcn_mfma_f32_16x16x32_bf16(bw[0][3], ah3, c0, 0, 0, 0); \
        c1 = __builtin_amdgcn_mfma_f32_16x16x32_bf16(bw[1][3], ah3, c1, 0, 0, 0); \
        _Pragma("unroll")                                                       \
        for (int ti = 0; ti < 2; ++ti) {                                        \
            f32x4 s = ti ? (a1 + c1) : (a0 + c0);                               \
            bf16x4 w;                                                           \
            _Pragma("unroll")                                                   \
            for (int r = 0; r < 4; ++r) {                                       \
                float v = s[r];                                                 \
                w[r] = (__bf16)(v > 0.f ? v : 0.f);                             \
            }                                                                   \
            *(bf16x4*)(&Hb[rb ^ 1][hswz(ln15, nt0 * 2 + ti * 32 + lg * 8)]) = w; \
        }                                                                       \
        STGW                                                                    \
        __syncthreads();                                                        \
    }

#define STG_LOAD(T)                                                             \
        if (((T) + 4 < T_STEPS) && xthr) {                                      \
            sx0 = *(const f32x2*)(xbase + (size_t)((T) + 4) * IN_D);            \
            sx1 = *(const f32x2*)(xbase + (size_t)((T) + 5) * IN_D);            \
            sx2 = *(const f32x2*)(xbase + (size_t)((T) + 6) * IN_D);            \
            sx3 = *(const f32x2*)(xbase + (size_t)((T) + 7) * IN_D);            \
        }
#define STG_WRITE(T)                                                            \
        if (((T) + 4 < T_STEPS) && xthr) {                                      \
            unsigned int p0 = ((unsigned int)f2bfbits(sx0[1]) << 16) | f2bfbits(sx0[0]); \
            unsigned int p1 = ((unsigned int)f2bfbits(sx1[1]) << 16) | f2bfbits(sx1[0]); \
            unsigned int p2 = ((unsigned int)f2bfbits(sx2[1]) << 16) | f2bfbits(sx2[0]); \
            unsigned int p3 = ((unsigned int)f2bfbits(sx3[1]) << 16) | f2bfbits(sx3[0]); \
            *(unsigned int*)(&Xs[(((T) + 4) & 7) * 1024 + xrow * 64 + xpair * 4]) = p0; \
            *(unsigned int*)(&Xs[(((T) + 5) & 7) * 1024 + xrow * 64 + xpair * 4]) = p1; \
            *(unsigned int*)(&Xs[(((T) + 6) & 7) * 1024 + xrow * 64 + xpair * 4]) = p2; \
            *(unsigned int*)(&Xs[(((T) + 7) & 7) * 1024 + xrow * 64 + xpair * 4]) = p3; \
        }

    for (int t = 0; t < T_STEPS; t += 8) {
        STEP(t + 0, STG_LOAD(t + 0), STG_WRITE(t + 0))
        STEP(t + 1, , )
        STEP(t + 2, , )
        STEP(t + 3, , )
        STEP(t + 4, STG_LOAD(t + 4), STG_WRITE(t + 4))
        STEP(t + 5, , )
        STEP(t + 6, , )
        STEP(t + 7, , )
    }
#undef STEP
#undef STG_LOAD
#undef STG_WRITE
    // after t=255 (rb=1) the final h sits in Hb[0]; loop's last barrier done

    // ================= epilogue (verified r7) =================
    // h_final -> d_out second segment (f32)
    {
        int row = tid >> 4, cg = tid & 15;
        bf16x8 hv = *(const bf16x8*)(&Hb[0][hswz(row, cg * 16)]);
        float* po = out + (size_t)B_TOT * OUT_D + (size_t)(b0 + row) * HID + cg * 8;
        #pragma unroll
        for (int e = 0; e < 8; ++e) po[e] = bf2f(hv[e]);
    }
    // projection (transposed form): D[o][batch], A = W_ho frag, B = h frag.
    bf16x8 af[4];
    #pragma unroll
    for (int kc = 0; kc < 4; ++kc)
        af[kc] = *(const bf16x8*)(&Hb[0][hswz(ln15, kc * 64 + lg * 16)]);

    for (int nt = wv; nt < 49; nt += 4) {
        f32x4 acc = *(const f32x4*)(b_ho + nt * 16 + 4 * lg);
        #pragma unroll
        for (int kc = 0; kc < 4; ++kc) {
            const float* p = W_ho + (nt * 16 + ln15) * HID + kc * 32 + lg * 8;
            bf16x8 bfrag;
            #pragma unroll
            for (int e = 0; e < 8; ++e) bfrag[e] = (__bf16)p[e];
            acc = __builtin_amdgcn_mfma_f32_16x16x32_bf16(bfrag, af[kc], acc, 0, 0, 0);
        }
        // lane holds batch=ln15, o = nt*16 + 4lg + r -> one dwordx4 store
        *(f32x4*)(out + (size_t)(b0 + ln15) * OUT_D + nt * 16 + 4 * lg) = acc;
    }
}

extern "C" void kernel_launch(void* const* d_in, const int* in_sizes, int n_in,
                              void* d_out, int out_size, void* d_ws, size_t ws_size,
                              hipStream_t stream) {
    const float* x    = (const float*)d_in[0];
    const float* h0   = (const float*)d_in[1];
    const float* W_ih = (const float*)d_in[2];
    const float* b_ih = (const float*)d_in[3];
    const float* W_hh = (const float*)d_in[4];
    const float* b_hh = (const float*)d_in[5];
    const float* W_ho = (const float*)d_in[6];
    const float* b_ho = (const float*)d_in[7];
    rnn_fused<<<B_TOT / BM, 256, 0, stream>>>(x, h0, W_ih, b_ih, W_hh, b_hh,
                                              W_ho, b_ho, (float*)d_out);
}

// Round 13
// 96.970 us; speedup vs baseline: 1.9048x; 1.0782x over previous
//
#include <hip/hip_runtime.h>
#include <hip/hip_bf16.h>

#define B_TOT   4096
#define T_STEPS 256
#define IN_D    28
#define HID     128
#define OUT_D   784
#define BM      16

typedef __bf16 bf16x8 __attribute__((ext_vector_type(8)));
typedef __bf16 bf16x4 __attribute__((ext_vector_type(4)));
typedef float  f32x4  __attribute__((ext_vector_type(4)));
typedef float  f32x2  __attribute__((ext_vector_type(2)));

__device__ __forceinline__ float bf2f(__bf16 b) {
    unsigned short s = __builtin_bit_cast(unsigned short, b);
    unsigned int u = ((unsigned int)s) << 16;
    return __builtin_bit_cast(float, u);
}
__device__ __forceinline__ unsigned short f2bfbits(float f) {
    unsigned int u = __builtin_bit_cast(unsigned int, f);
    u += 0x7fffu + ((u >> 16) & 1u);   // RNE (finite values)
    return (unsigned short)(u >> 16);
}

// H LDS layout: [16 rows b][128 bf16 n] = 256 B/row, XOR-swizzled (verified r7).
__device__ __forceinline__ int hswz(int row, int byteInRow) {
    return row * 256 + (byteInRow ^ ((row & 7) << 4));
}

// 8 waves (512 threads) -> 2 waves per SIMD so ds_read latency, MFMA dep
// stalls, write drain and barrier skew of one wave hide under the other
// wave's issue. Each wave owns ONE 16-col n-tile: 5 MFMAs/step.
__global__ __launch_bounds__(512) void rnn_fused(
    const float* __restrict__ x,     // [B,T,IN] f32
    const float* __restrict__ h0,    // [B,HID] f32
    const float* __restrict__ W_ih,  // [HID,IN] f32
    const float* __restrict__ b_ih,  // [HID] f32
    const float* __restrict__ W_hh,  // [HID,HID] f32
    const float* __restrict__ b_hh,  // [HID] f32
    const float* __restrict__ W_ho,  // [OUT_D,HID] f32
    const float* __restrict__ b_ho,  // [OUT_D] f32
    float* __restrict__ out)         // [B*OUT_D] f32, then [B*HID] f32
{
    __shared__ __align__(16) unsigned char Hb[2][BM * 256]; // h (bf16) double buffer
    __shared__ __align__(16) unsigned char Xs[8 * 1024];    // x ring: 8 slots x [16 rows][64B]

    const int tid  = threadIdx.x;
    const int lane = tid & 63;
    const int wv   = tid >> 6;       // wave 0..7
    const int ln15 = lane & 15;
    const int lg   = lane >> 4;      // k-group 0..3
    const int b0   = blockIdx.x * BM;

    // ---- Weight fragments (f32 -> bf16), register-resident, MFMA *A* operand:
    // A[m = n_out][k], lane: m = nt0 + ln15, k = 8*lg + e.  (mapping verified r7)
    const int nt0 = wv * 16;         // this wave owns hidden cols [nt0, nt0+16)
    bf16x8 bw[4];
    #pragma unroll
    for (int kc = 0; kc < 4; ++kc) {
        const float* p = W_hh + (nt0 + ln15) * HID + kc * 32 + lg * 8;
        bf16x8 v;
        #pragma unroll
        for (int e = 0; e < 8; ++e) v[e] = (__bf16)p[e];
        bw[kc] = v;
    }
    const __bf16 bzero = (__bf16)0.0f;
    bf16x8 bxf;
    {
        int n = nt0 + ln15;
        #pragma unroll
        for (int e = 0; e < 8; ++e) {
            int k = lg * 8 + e;
            bxf[e] = (k < IN_D) ? (__bf16)W_ih[n * IN_D + k] : bzero;  // zero-pad K 28->32
        }
    }
    // bias per lane: D row = n_out = nt0 + 4*lg + r  (4 consecutive)
    f32x4 bias4;
    {
        int n = nt0 + 4 * lg;
        f32x4 bi = *(const f32x4*)(b_ih + n);
        f32x4 bh = *(const f32x4*)(b_hh + n);
        bias4 = bi + bh;
    }

    // ---- stage initial hidden into Hb[0] (f32 -> bf16): first 256 threads
    if (tid < 256) {
        int row = tid >> 4, cg = tid & 15;
        const float* p = h0 + (size_t)(b0 + row) * HID + cg * 8;
        bf16x8 hv;
        #pragma unroll
        for (int e = 0; e < 8; ++e) hv[e] = (__bf16)p[e];
        *(bf16x8*)(&Hb[0][hswz(row, cg * 16)]) = hv;
    }
    // ---- zero the k=28..31 pad of all 8 X ring slots (never rewritten)
    if (tid < 256) {
        int slot = tid >> 5, idx = tid & 31, row = idx >> 1, d = idx & 1;
        *(unsigned int*)(&Xs[slot * 1024 + row * 64 + 56 + d * 4]) = 0u;
    }
    // ---- x staging geometry (verified r7): 224 threads, 16 rows x 14 dword-pairs
    const int xrow = tid / 14, xpair = tid % 14;
    const bool xthr = (tid < 224);
    const float* xbase = x + (size_t)(b0 + xrow) * T_STEPS * IN_D + xpair * 2;
    // ---- pre-stage steps 0..3 into slots 0..3
    if (xthr) {
        #pragma unroll
        for (int s = 0; s < 4; ++s) {
            f32x2 v = *(const f32x2*)(xbase + (size_t)s * IN_D);
            unsigned int pk = ((unsigned int)f2bfbits(v[1]) << 16) | f2bfbits(v[0]);
            *(unsigned int*)(&Xs[s * 1024 + xrow * 64 + xpair * 4]) = pk;
        }
    }
    f32x2 sx0 = {0.f, 0.f}, sx1 = sx0, sx2 = sx0, sx3 = sx0;
    __syncthreads();

    // ================= recurrence: 256 steps, 1 barrier/step =================
    // Transposed MFMA (verified r7): D[n_out][batch] = W * h^T. Per wave:
    // 1 x-MFMA + 4 h-MFMAs on its 16-col n-tile; lane holds batch=ln15,
    // n_out = nt0 + 4lg + r -> ONE ds_write_b64 per step.
#define STEP(T, STGL, STGW)                                                     \
    {                                                                           \
        const int rb = (T) & 1;                                                 \
        STGL                                                                    \
        bf16x8 ax  = *(const bf16x8*)(&Xs[((T) & 7) * 1024 + ln15 * 64 + lg * 16]); \
        bf16x8 ah0 = *(const bf16x8*)(&Hb[rb][hswz(ln15,   0 + lg * 16)]);      \
        bf16x8 ah1 = *(const bf16x8*)(&Hb[rb][hswz(ln15,  64 + lg * 16)]);      \
        bf16x8 ah2 = *(const bf16x8*)(&Hb[rb][hswz(ln15, 128 + lg * 16)]);      \
        bf16x8 ah3 = *(const bf16x8*)(&Hb[rb][hswz(ln15, 192 + lg * 16)]);      \
        f32x4 zz = {0.f, 0.f, 0.f, 0.f};                                        \
        f32x4 a = __builtin_amdgcn_mfma_f32_16x16x32_bf16(bxf,   ax,  bias4, 0, 0, 0); \
        f32x4 c = __builtin_amdgcn_mfma_f32_16x16x32_bf16(bw[1], ah1, zz, 0, 0, 0); \
        a = __builtin_amdgcn_mfma_f32_16x16x32_bf16(bw[0], ah0, a, 0, 0, 0);    \
        c = __builtin_amdgcn_mfma_f32_16x16x32_bf16(bw[3], ah3, c, 0, 0, 0);    \
        a = __builtin_amdgcn_mfma_f32_16x16x32_bf16(bw[2], ah2, a, 0, 0, 0);    \
        f32x4 s = a + c;                                                        \
        bf16x4 w;                                                               \
        _Pragma("unroll")                                                       \
        for (int r = 0; r < 4; ++r) {                                           \
            float v = s[r];                                                     \
            w[r] = (__bf16)(v > 0.f ? v : 0.f);                                 \
        }                                                                       \
        *(bf16x4*)(&Hb[rb ^ 1][hswz(ln15, nt0 * 2 + lg * 8)]) = w;              \
        STGW                                                                    \
        __syncthreads();                                                        \
    }

#define STG_LOAD(T)                                                             \
        if (((T) + 4 < T_STEPS) && xthr) {                                      \
            sx0 = *(const f32x2*)(xbase + (size_t)((T) + 4) * IN_D);            \
            sx1 = *(const f32x2*)(xbase + (size_t)((T) + 5) * IN_D);            \
            sx2 = *(const f32x2*)(xbase + (size_t)((T) + 6) * IN_D);            \
            sx3 = *(const f32x2*)(xbase + (size_t)((T) + 7) * IN_D);            \
        }
#define STG_WRITE(T)                                                            \
        if (((T) + 4 < T_STEPS) && xthr) {                                      \
            unsigned int p0 = ((unsigned int)f2bfbits(sx0[1]) << 16) | f2bfbits(sx0[0]); \
            unsigned int p1 = ((unsigned int)f2bfbits(sx1[1]) << 16) | f2bfbits(sx1[0]); \
            unsigned int p2 = ((unsigned int)f2bfbits(sx2[1]) << 16) | f2bfbits(sx2[0]); \
            unsigned int p3 = ((unsigned int)f2bfbits(sx3[1]) << 16) | f2bfbits(sx3[0]); \
            *(unsigned int*)(&Xs[(((T) + 4) & 7) * 1024 + xrow * 64 + xpair * 4]) = p0; \
            *(unsigned int*)(&Xs[(((T) + 5) & 7) * 1024 + xrow * 64 + xpair * 4]) = p1; \
            *(unsigned int*)(&Xs[(((T) + 6) & 7) * 1024 + xrow * 64 + xpair * 4]) = p2; \
            *(unsigned int*)(&Xs[(((T) + 7) & 7) * 1024 + xrow * 64 + xpair * 4]) = p3; \
        }

    for (int t = 0; t < T_STEPS; t += 8) {
        STEP(t + 0, STG_LOAD(t + 0), STG_WRITE(t + 0))
        STEP(t + 1, , )
        STEP(t + 2, , )
        STEP(t + 3, , )
        STEP(t + 4, STG_LOAD(t + 4), STG_WRITE(t + 4))
        STEP(t + 5, , )
        STEP(t + 6, , )
        STEP(t + 7, , )
    }
#undef STEP
#undef STG_LOAD
#undef STG_WRITE
    // after t=255 (rb=1) the final h sits in Hb[0]; loop's last barrier done

    // ================= epilogue (verified r7) =================
    // h_final -> d_out second segment (f32)
    if (tid < 256) {
        int row = tid >> 4, cg = tid & 15;
        bf16x8 hv = *(const bf16x8*)(&Hb[0][hswz(row, cg * 16)]);
        float* po = out + (size_t)B_TOT * OUT_D + (size_t)(b0 + row) * HID + cg * 8;
        #pragma unroll
        for (int e = 0; e < 8; ++e) po[e] = bf2f(hv[e]);
    }
    // projection (transposed form): D[o][batch], A = W_ho frag, B = h frag.
    bf16x8 af[4];
    #pragma unroll
    for (int kc = 0; kc < 4; ++kc)
        af[kc] = *(const bf16x8*)(&Hb[0][hswz(ln15, kc * 64 + lg * 16)]);

    for (int nt = wv; nt < 49; nt += 8) {
        f32x4 acc = *(const f32x4*)(b_ho + nt * 16 + 4 * lg);
        #pragma unroll
        for (int kc = 0; kc < 4; ++kc) {
            const float* p = W_ho + (nt * 16 + ln15) * HID + kc * 32 + lg * 8;
            bf16x8 bfrag;
            #pragma unroll
            for (int e = 0; e < 8; ++e) bfrag[e] = (__bf16)p[e];
            acc = __builtin_amdgcn_mfma_f32_16x16x32_bf16(bfrag, af[kc], acc, 0, 0, 0);
        }
        // lane holds batch=ln15, o = nt*16 + 4lg + r -> one dwordx4 store
        *(f32x4*)(out + (size_t)(b0 + ln15) * OUT_D + nt * 16 + 4 * lg) = acc;
    }
}

extern "C" void kernel_launch(void* const* d_in, const int* in_sizes, int n_in,
                              void* d_out, int out_size, void* d_ws, size_t ws_size,
                              hipStream_t stream) {
    const float* x    = (const float*)d_in[0];
    const float* h0   = (const float*)d_in[1];
    const float* W_ih = (const float*)d_in[2];
    const float* b_ih = (const float*)d_in[3];
    const float* W_hh = (const float*)d_in[4];
    const float* b_hh = (const float*)d_in[5];
    const float* W_ho = (const float*)d_in[6];
    const float* b_ho = (const float*)d_in[7];
    rnn_fused<<<B_TOT / BM, 512, 0, stream>>>(x, h0, W_ih, b_ih, W_hh, b_hh,
                                              W_ho, b_ho, (float*)d_out);
}

// Round 14
// 96.169 us; speedup vs baseline: 1.9207x; 1.0083x over previous
//
#include <hip/hip_runtime.h>
#include <hip/hip_bf16.h>

#define B_TOT   4096
#define T_STEPS 256
#define IN_D    28
#define HID     128
#define OUT_D   784
#define BM      16

typedef __bf16 bf16x8 __attribute__((ext_vector_type(8)));
typedef __bf16 bf16x4 __attribute__((ext_vector_type(4)));
typedef float  f32x4  __attribute__((ext_vector_type(4)));
typedef float  f32x2  __attribute__((ext_vector_type(2)));

__device__ __forceinline__ float bf2f(__bf16 b) {
    unsigned short s = __builtin_bit_cast(unsigned short, b);
    unsigned int u = ((unsigned int)s) << 16;
    return __builtin_bit_cast(float, u);
}
__device__ __forceinline__ unsigned short f2bfbits(float f) {
    unsigned int u = __builtin_bit_cast(unsigned int, f);
    u += 0x7fffu + ((u >> 16) & 1u);   // RNE (finite values)
    return (unsigned short)(u >> 16);
}

// Swizzled row layout (verified r7..r13): row stride 256B, byte ^= (row&7)<<4.
// 16-lane b128 read groups land 2-way (free, m136) instead of 8/16-way.
__device__ __forceinline__ int hswz(int row, int byteInRow) {
    return row * 256 + (byteInRow ^ ((row & 7) << 4));
}

// 8 waves (512 threads) -> 2 waves per SIMD: ds_read latency, MFMA dep stalls
// and barrier skew of one wave hide under the other wave's issue (r13: +8%).
// r14 change: Xs ring slots use the SAME swizzled 256B-stride layout as Hb —
// the old 64B-stride slots made every ax read an 8-way bank conflict
// (13.1M conflict-cycles/dispatch ~= 200 cyc/step, the measured delta).
__global__ __launch_bounds__(512) void rnn_fused(
    const float* __restrict__ x,     // [B,T,IN] f32
    const float* __restrict__ h0,    // [B,HID] f32
    const float* __restrict__ W_ih,  // [HID,IN] f32
    const float* __restrict__ b_ih,  // [HID] f32
    const float* __restrict__ W_hh,  // [HID,HID] f32
    const float* __restrict__ b_hh,  // [HID] f32
    const float* __restrict__ W_ho,  // [OUT_D,HID] f32
    const float* __restrict__ b_ho,  // [OUT_D] f32
    float* __restrict__ out)         // [B*OUT_D] f32, then [B*HID] f32
{
    __shared__ __align__(16) unsigned char Hb[2][BM * 256]; // h (bf16) double buffer
    __shared__ __align__(16) unsigned char Xs[8 * BM * 256];// x ring: 8 swizzled slots

    const int tid  = threadIdx.x;
    const int lane = tid & 63;
    const int wv   = tid >> 6;       // wave 0..7
    const int ln15 = lane & 15;
    const int lg   = lane >> 4;      // k-group 0..3
    const int b0   = blockIdx.x * BM;

    // ---- Weight fragments (f32 -> bf16), register-resident, MFMA *A* operand:
    // A[m = n_out][k], lane: m = nt0 + ln15, k = 8*lg + e.  (mapping verified r7)
    const int nt0 = wv * 16;         // this wave owns hidden cols [nt0, nt0+16)
    bf16x8 bw[4];
    #pragma unroll
    for (int kc = 0; kc < 4; ++kc) {
        const float* p = W_hh + (nt0 + ln15) * HID + kc * 32 + lg * 8;
        bf16x8 v;
        #pragma unroll
        for (int e = 0; e < 8; ++e) v[e] = (__bf16)p[e];
        bw[kc] = v;
    }
    const __bf16 bzero = (__bf16)0.0f;
    bf16x8 bxf;
    {
        int n = nt0 + ln15;
        #pragma unroll
        for (int e = 0; e < 8; ++e) {
            int k = lg * 8 + e;
            bxf[e] = (k < IN_D) ? (__bf16)W_ih[n * IN_D + k] : bzero;  // zero-pad K 28->32
        }
    }
    // bias per lane: D row = n_out = nt0 + 4*lg + r  (4 consecutive)
    f32x4 bias4;
    {
        int n = nt0 + 4 * lg;
        f32x4 bi = *(const f32x4*)(b_ih + n);
        f32x4 bh = *(const f32x4*)(b_hh + n);
        bias4 = bi + bh;
    }

    // ---- stage initial hidden into Hb[0] (f32 -> bf16): first 256 threads
    if (tid < 256) {
        int row = tid >> 4, cg = tid & 15;
        const float* p = h0 + (size_t)(b0 + row) * HID + cg * 8;
        bf16x8 hv;
        #pragma unroll
        for (int e = 0; e < 8; ++e) hv[e] = (__bf16)p[e];
        *(bf16x8*)(&Hb[0][hswz(row, cg * 16)]) = hv;
    }
    // ---- zero the k=28..31 pad (bytes 56..63 of each row) of all 8 ring slots
    if (tid < 256) {
        int slot = tid >> 5, idx = tid & 31, row = idx >> 1, d = idx & 1;
        *(unsigned int*)(&Xs[slot * (BM * 256) + hswz(row, 56 + d * 4)]) = 0u;
    }
    // ---- x staging geometry (verified r7): 224 threads, 16 rows x 14 dword-pairs
    const int xrow = tid / 14, xpair = tid % 14;
    const bool xthr = (tid < 224);
    const float* xbase = x + (size_t)(b0 + xrow) * T_STEPS * IN_D + xpair * 2;
    // ---- pre-stage steps 0..3 into slots 0..3
    if (xthr) {
        #pragma unroll
        for (int s = 0; s < 4; ++s) {
            f32x2 v = *(const f32x2*)(xbase + (size_t)s * IN_D);
            unsigned int pk = ((unsigned int)f2bfbits(v[1]) << 16) | f2bfbits(v[0]);
            *(unsigned int*)(&Xs[s * (BM * 256) + hswz(xrow, xpair * 4)]) = pk;
        }
    }
    f32x2 sx0 = {0.f, 0.f}, sx1 = sx0, sx2 = sx0, sx3 = sx0;
    __syncthreads();

    // ================= recurrence: 256 steps, 1 barrier/step =================
    // Transposed MFMA (verified r7): D[n_out][batch] = W * h^T. Per wave:
    // 1 x-MFMA + 4 h-MFMAs on its 16-col n-tile; lane holds batch=ln15,
    // n_out = nt0 + 4lg + r -> ONE ds_write_b64 per step.
#define STEP(T, STGL, STGW)                                                     \
    {                                                                           \
        const int rb = (T) & 1;                                                 \
        STGL                                                                    \
        bf16x8 ax  = *(const bf16x8*)(&Xs[((T) & 7) * (BM * 256) + hswz(ln15, lg * 16)]); \
        bf16x8 ah0 = *(const bf16x8*)(&Hb[rb][hswz(ln15,   0 + lg * 16)]);      \
        bf16x8 ah1 = *(const bf16x8*)(&Hb[rb][hswz(ln15,  64 + lg * 16)]);      \
        bf16x8 ah2 = *(const bf16x8*)(&Hb[rb][hswz(ln15, 128 + lg * 16)]);      \
        bf16x8 ah3 = *(const bf16x8*)(&Hb[rb][hswz(ln15, 192 + lg * 16)]);      \
        f32x4 zz = {0.f, 0.f, 0.f, 0.f};                                        \
        f32x4 a = __builtin_amdgcn_mfma_f32_16x16x32_bf16(bxf,   ax,  bias4, 0, 0, 0); \
        f32x4 c = __builtin_amdgcn_mfma_f32_16x16x32_bf16(bw[1], ah1, zz, 0, 0, 0); \
        a = __builtin_amdgcn_mfma_f32_16x16x32_bf16(bw[0], ah0, a, 0, 0, 0);    \
        c = __builtin_amdgcn_mfma_f32_16x16x32_bf16(bw[3], ah3, c, 0, 0, 0);    \
        a = __builtin_amdgcn_mfma_f32_16x16x32_bf16(bw[2], ah2, a, 0, 0, 0);    \
        f32x4 s = a + c;                                                        \
        bf16x4 w;                                                               \
        _Pragma("unroll")                                                       \
        for (int r = 0; r < 4; ++r) {                                           \
            float v = s[r];                                                     \
            w[r] = (__bf16)(v > 0.f ? v : 0.f);                                 \
        }                                                                       \
        *(bf16x4*)(&Hb[rb ^ 1][hswz(ln15, nt0 * 2 + lg * 8)]) = w;              \
        STGW                                                                    \
        __syncthreads();                                                        \
    }

#define STG_LOAD(T)                                                             \
        if (((T) + 4 < T_STEPS) && xthr) {                                      \
            sx0 = *(const f32x2*)(xbase + (size_t)((T) + 4) * IN_D);            \
            sx1 = *(const f32x2*)(xbase + (size_t)((T) + 5) * IN_D);            \
            sx2 = *(const f32x2*)(xbase + (size_t)((T) + 6) * IN_D);            \
            sx3 = *(const f32x2*)(xbase + (size_t)((T) + 7) * IN_D);            \
        }
#define STG_WRITE(T)                                                            \
        if (((T) + 4 < T_STEPS) && xthr) {                                      \
            unsigned int p0 = ((unsigned int)f2bfbits(sx0[1]) << 16) | f2bfbits(sx0[0]); \
            unsigned int p1 = ((unsigned int)f2bfbits(sx1[1]) << 16) | f2bfbits(sx1[0]); \
            unsigned int p2 = ((unsigned int)f2bfbits(sx2[1]) << 16) | f2bfbits(sx2[0]); \
            unsigned int p3 = ((unsigned int)f2bfbits(sx3[1]) << 16) | f2bfbits(sx3[0]); \
            *(unsigned int*)(&Xs[(((T) + 4) & 7) * (BM * 256) + hswz(xrow, xpair * 4)]) = p0; \
            *(unsigned int*)(&Xs[(((T) + 5) & 7) * (BM * 256) + hswz(xrow, xpair * 4)]) = p1; \
            *(unsigned int*)(&Xs[(((T) + 6) & 7) * (BM * 256) + hswz(xrow, xpair * 4)]) = p2; \
            *(unsigned int*)(&Xs[(((T) + 7) & 7) * (BM * 256) + hswz(xrow, xpair * 4)]) = p3; \
        }

    for (int t = 0; t < T_STEPS; t += 8) {
        STEP(t + 0, STG_LOAD(t + 0), STG_WRITE(t + 0))
        STEP(t + 1, , )
        STEP(t + 2, , )
        STEP(t + 3, , )
        STEP(t + 4, STG_LOAD(t + 4), STG_WRITE(t + 4))
        STEP(t + 5, , )
        STEP(t + 6, , )
        STEP(t + 7, , )
    }
#undef STEP
#undef STG_LOAD
#undef STG_WRITE
    // after t=255 (rb=1) the final h sits in Hb[0]; loop's last barrier done

    // ================= epilogue (verified r7) =================
    // h_final -> d_out second segment (f32)
    if (tid < 256) {
        int row = tid >> 4, cg = tid & 15;
        bf16x8 hv = *(const bf16x8*)(&Hb[0][hswz(row, cg * 16)]);
        float* po = out + (size_t)B_TOT * OUT_D + (size_t)(b0 + row) * HID + cg * 8;
        #pragma unroll
        for (int e = 0; e < 8; ++e) po[e] = bf2f(hv[e]);
    }
    // projection (transposed form): D[o][batch], A = W_ho frag, B = h frag.
    bf16x8 af[4];
    #pragma unroll
    for (int kc = 0; kc < 4; ++kc)
        af[kc] = *(const bf16x8*)(&Hb[0][hswz(ln15, kc * 64 + lg * 16)]);

    for (int nt = wv; nt < 49; nt += 8) {
        f32x4 acc = *(const f32x4*)(b_ho + nt * 16 + 4 * lg);
        #pragma unroll
        for (int kc = 0; kc < 4; ++kc) {
            const float* p = W_ho + (nt * 16 + ln15) * HID + kc * 32 + lg * 8;
            bf16x8 bfrag;
            #pragma unroll
            for (int e = 0; e < 8; ++e) bfrag[e] = (__bf16)p[e];
            acc = __builtin_amdgcn_mfma_f32_16x16x32_bf16(bfrag, af[kc], acc, 0, 0, 0);
        }
        // lane holds batch=ln15, o = nt*16 + 4lg + r -> one dwordx4 store
        *(f32x4*)(out + (size_t)(b0 + ln15) * OUT_D + nt * 16 + 4 * lg) = acc;
    }
}

extern "C" void kernel_launch(void* const* d_in, const int* in_sizes, int n_in,
                              void* d_out, int out_size, void* d_ws, size_t ws_size,
                              hipStream_t stream) {
    const float* x    = (const float*)d_in[0];
    const float* h0   = (const float*)d_in[1];
    const float* W_ih = (const float*)d_in[2];
    const float* b_ih = (const float*)d_in[3];
    const float* W_hh = (const float*)d_in[4];
    const float* b_hh = (const float*)d_in[5];
    const float* W_ho = (const float*)d_in[6];
    const float* b_ho = (const float*)d_in[7];
    rnn_fused<<<B_TOT / BM, 512, 0, stream>>>(x, h0, W_ih, b_ih, W_hh, b_hh,
                                              W_ho, b_ho, (float*)d_out);
}

// Round 15
// 86.340 us; speedup vs baseline: 2.1393x; 1.1138x over previous
//
#include <hip/hip_runtime.h>
#include <hip/hip_bf16.h>

#define B_TOT   4096
#define T_STEPS 256
#define IN_D    28
#define HID     128
#define OUT_D   784
#define BM      16

typedef __bf16 bf16x8 __attribute__((ext_vector_type(8)));
typedef __bf16 bf16x4 __attribute__((ext_vector_type(4)));
typedef float  f32x4  __attribute__((ext_vector_type(4)));
typedef float  f32x2  __attribute__((ext_vector_type(2)));

__device__ __forceinline__ float bf2f(__bf16 b) {
    unsigned short s = __builtin_bit_cast(unsigned short, b);
    unsigned int u = ((unsigned int)s) << 16;
    return __builtin_bit_cast(float, u);
}
__device__ __forceinline__ unsigned short f2bfbits(float f) {
    unsigned int u = __builtin_bit_cast(unsigned int, f);
    u += 0x7fffu + ((u >> 16) & 1u);   // RNE (finite values)
    return (unsigned short)(u >> 16);
}

// Swizzled row layout (verified r7..r14): row stride 256B, byte ^= (row&7)<<4.
__device__ __forceinline__ int hswz(int row, int byteInRow) {
    return row * 256 + (byteInRow ^ ((row & 7) << 4));
}

// Loop barrier: drains LDS (h-write ordering) but NOT vmcnt, so in-flight
// lane-private x prefetch loads survive the barrier. __syncthreads() would
// drain vmcnt(0) at every step and expose HBM latency to all 8 waves.
#define BARLDS() asm volatile("s_waitcnt lgkmcnt(0)\n\ts_barrier" ::: "memory")

// 8 waves (512 threads) -> 2 waves/SIMD (r13: +8%). Each wave owns ONE
// 16-col n-tile: 5 MFMAs/step, ONE ds_write_b64/step.
__global__ __launch_bounds__(512) void rnn_fused(
    const float* __restrict__ x,     // [B,T,IN] f32
    const float* __restrict__ h0,    // [B,HID] f32
    const float* __restrict__ W_ih,  // [HID,IN] f32
    const float* __restrict__ b_ih,  // [HID] f32
    const float* __restrict__ W_hh,  // [HID,HID] f32
    const float* __restrict__ b_hh,  // [HID] f32
    const float* __restrict__ W_ho,  // [OUT_D,HID] f32
    const float* __restrict__ b_ho,  // [OUT_D] f32
    float* __restrict__ out)         // [B*OUT_D] f32, then [B*HID] f32
{
    __shared__ __align__(16) unsigned char Hb[2][BM * 256]; // h (bf16) double buffer
    __shared__ __align__(16) unsigned char Xs[8 * BM * 256];// x ring: 8 swizzled slots

    const int tid  = threadIdx.x;
    const int lane = tid & 63;
    const int wv   = tid >> 6;       // wave 0..7
    const int ln15 = lane & 15;
    const int lg   = lane >> 4;      // k-group 0..3
    const int b0   = blockIdx.x * BM;

    // ---- Weight fragments (f32 -> bf16), register-resident, MFMA *A* operand:
    // A[m = n_out][k], lane: m = nt0 + ln15, k = 8*lg + e.  (verified r7)
    const int nt0 = wv * 16;         // this wave owns hidden cols [nt0, nt0+16)
    bf16x8 bw[4];
    #pragma unroll
    for (int kc = 0; kc < 4; ++kc) {
        const float* p = W_hh + (nt0 + ln15) * HID + kc * 32 + lg * 8;
        bf16x8 v;
        #pragma unroll
        for (int e = 0; e < 8; ++e) v[e] = (__bf16)p[e];
        bw[kc] = v;
    }
    const __bf16 bzero = (__bf16)0.0f;
    bf16x8 bxf;
    {
        int n = nt0 + ln15;
        #pragma unroll
        for (int e = 0; e < 8; ++e) {
            int k = lg * 8 + e;
            bxf[e] = (k < IN_D) ? (__bf16)W_ih[n * IN_D + k] : bzero;  // zero-pad K 28->32
        }
    }
    // bias per lane: D row = n_out = nt0 + 4*lg + r  (4 consecutive)
    f32x4 bias4;
    {
        int n = nt0 + 4 * lg;
        f32x4 bi = *(const f32x4*)(b_ih + n);
        f32x4 bh = *(const f32x4*)(b_hh + n);
        bias4 = bi + bh;
    }

    // ---- stage initial hidden into Hb[0] (f32 -> bf16): first 256 threads
    if (tid < 256) {
        int row = tid >> 4, cg = tid & 15;
        const float* p = h0 + (size_t)(b0 + row) * HID + cg * 8;
        bf16x8 hv;
        #pragma unroll
        for (int e = 0; e < 8; ++e) hv[e] = (__bf16)p[e];
        *(bf16x8*)(&Hb[0][hswz(row, cg * 16)]) = hv;
    }
    // ---- zero the k=28..31 pad (bytes 56..63 of each row) of all 8 ring slots
    if (tid < 256) {
        int slot = tid >> 5, idx = tid & 31, row = idx >> 1, d = idx & 1;
        *(unsigned int*)(&Xs[slot * (BM * 256) + hswz(row, 56 + d * 4)]) = 0u;
    }
    // ---- x staging geometry (verified r7): 224 threads, 16 rows x 14 dword-pairs
    const int xrow = tid / 14, xpair = tid % 14;
    const bool xthr = (tid < 224);
    const float* xbase = x + (size_t)(b0 + xrow) * T_STEPS * IN_D + xpair * 2;
    // ---- pre-stage steps 0..3 into slots 0..3
    if (xthr) {
        #pragma unroll
        for (int s = 0; s < 4; ++s) {
            f32x2 v = *(const f32x2*)(xbase + (size_t)s * IN_D);
            unsigned int pk = ((unsigned int)f2bfbits(v[1]) << 16) | f2bfbits(v[0]);
            *(unsigned int*)(&Xs[s * (BM * 256) + hswz(xrow, xpair * 4)]) = pk;
        }
    }
    f32x2 sx0 = {0.f, 0.f}, sx1 = sx0, sx2 = sx0, sx3 = sx0;
    __syncthreads();

    // ================= recurrence: 256 steps, 1 raw barrier/step =============
    // Consume path identical to r13/r14 (verified). Staging pipeline (NEW):
    //   step T   : issue 4 global loads (x_{T+4..T+7})      [STG_LOAD]
    //   step T+2 : vmcnt-wait (data ~1700cyc old), pack, 4 ds_writes [STG_WRITE]
    //   step T+4 : first read of those slots (>=1 barrier after write)
    // Slot disjointness: step T+2 reads slot (T+2)&7, writes (T+4..T+7)&7 ✓;
    // step T+6 writes (T+8..T+11)&7 = (T..T+3)&7, last read at step T+3 ✓.
#define STEP(T, STGL, STGW)                                                     \
    {                                                                           \
        const int rb = (T) & 1;                                                 \
        STGL                                                                    \
        bf16x8 ax  = *(const bf16x8*)(&Xs[((T) & 7) * (BM * 256) + hswz(ln15, lg * 16)]); \
        bf16x8 ah0 = *(const bf16x8*)(&Hb[rb][hswz(ln15,   0 + lg * 16)]);      \
        bf16x8 ah1 = *(const bf16x8*)(&Hb[rb][hswz(ln15,  64 + lg * 16)]);      \
        bf16x8 ah2 = *(const bf16x8*)(&Hb[rb][hswz(ln15, 128 + lg * 16)]);      \
        bf16x8 ah3 = *(const bf16x8*)(&Hb[rb][hswz(ln15, 192 + lg * 16)]);      \
        f32x4 zz = {0.f, 0.f, 0.f, 0.f};                                        \
        f32x4 a = __builtin_amdgcn_mfma_f32_16x16x32_bf16(bxf,   ax,  bias4, 0, 0, 0); \
        f32x4 c = __builtin_amdgcn_mfma_f32_16x16x32_bf16(bw[1], ah1, zz, 0, 0, 0); \
        a = __builtin_amdgcn_mfma_f32_16x16x32_bf16(bw[0], ah0, a, 0, 0, 0);    \
        c = __builtin_amdgcn_mfma_f32_16x16x32_bf16(bw[3], ah3, c, 0, 0, 0);    \
        a = __builtin_amdgcn_mfma_f32_16x16x32_bf16(bw[2], ah2, a, 0, 0, 0);    \
        f32x4 s = a + c;                                                        \
        bf16x4 w;                                                               \
        _Pragma("unroll")                                                       \
        for (int r = 0; r < 4; ++r) {                                           \
            float v = s[r];                                                     \
            w[r] = (__bf16)(v > 0.f ? v : 0.f);                                 \
        }                                                                       \
        *(bf16x4*)(&Hb[rb ^ 1][hswz(ln15, nt0 * 2 + lg * 8)]) = w;              \
        STGW                                                                    \
        BARLDS();                                                               \
    }

#define STG_LOAD(T)                                                             \
        if (((T) + 4 < T_STEPS) && xthr) {                                      \
            sx0 = *(const f32x2*)(xbase + (size_t)((T) + 4) * IN_D);            \
            sx1 = *(const f32x2*)(xbase + (size_t)((T) + 5) * IN_D);            \
            sx2 = *(const f32x2*)(xbase + (size_t)((T) + 6) * IN_D);            \
            sx3 = *(const f32x2*)(xbase + (size_t)((T) + 7) * IN_D);            \
        }
#define STG_WRITE(T)                                                            \
        if (((T) + 4 < T_STEPS) && xthr) {                                      \
            unsigned int p0 = ((unsigned int)f2bfbits(sx0[1]) << 16) | f2bfbits(sx0[0]); \
            unsigned int p1 = ((unsigned int)f2bfbits(sx1[1]) << 16) | f2bfbits(sx1[0]); \
            unsigned int p2 = ((unsigned int)f2bfbits(sx2[1]) << 16) | f2bfbits(sx2[0]); \
            unsigned int p3 = ((unsigned int)f2bfbits(sx3[1]) << 16) | f2bfbits(sx3[0]); \
            *(unsigned int*)(&Xs[(((T) + 4) & 7) * (BM * 256) + hswz(xrow, xpair * 4)]) = p0; \
            *(unsigned int*)(&Xs[(((T) + 5) & 7) * (BM * 256) + hswz(xrow, xpair * 4)]) = p1; \
            *(unsigned int*)(&Xs[(((T) + 6) & 7) * (BM * 256) + hswz(xrow, xpair * 4)]) = p2; \
            *(unsigned int*)(&Xs[(((T) + 7) & 7) * (BM * 256) + hswz(xrow, xpair * 4)]) = p3; \
        }

    for (int t = 0; t < T_STEPS; t += 8) {
        STEP(t + 0, STG_LOAD(t + 0), )
        STEP(t + 1, , )
        STEP(t + 2, , STG_WRITE(t + 0))
        STEP(t + 3, , )
        STEP(t + 4, STG_LOAD(t + 4), )
        STEP(t + 5, , )
        STEP(t + 6, , STG_WRITE(t + 4))
        STEP(t + 7, , )
    }
#undef STEP
#undef STG_LOAD
#undef STG_WRITE
    // after t=255 (rb=1) the final h sits in Hb[0]; loop's last BARLDS done

    // ================= epilogue (verified r7) =================
    // h_final -> d_out second segment (f32)
    if (tid < 256) {
        int row = tid >> 4, cg = tid & 15;
        bf16x8 hv = *(const bf16x8*)(&Hb[0][hswz(row, cg * 16)]);
        float* po = out + (size_t)B_TOT * OUT_D + (size_t)(b0 + row) * HID + cg * 8;
        #pragma unroll
        for (int e = 0; e < 8; ++e) po[e] = bf2f(hv[e]);
    }
    // projection (transposed form): D[o][batch], A = W_ho frag, B = h frag.
    bf16x8 af[4];
    #pragma unroll
    for (int kc = 0; kc < 4; ++kc)
        af[kc] = *(const bf16x8*)(&Hb[0][hswz(ln15, kc * 64 + lg * 16)]);

    for (int nt = wv; nt < 49; nt += 8) {
        f32x4 acc = *(const f32x4*)(b_ho + nt * 16 + 4 * lg);
        #pragma unroll
        for (int kc = 0; kc < 4; ++kc) {
            const float* p = W_ho + (nt * 16 + ln15) * HID + kc * 32 + lg * 8;
            bf16x8 bfrag;
            #pragma unroll
            for (int e = 0; e < 8; ++e) bfrag[e] = (__bf16)p[e];
            acc = __builtin_amdgcn_mfma_f32_16x16x32_bf16(bfrag, af[kc], acc, 0, 0, 0);
        }
        // lane holds batch=ln15, o = nt*16 + 4lg + r -> one dwordx4 store
        *(f32x4*)(out + (size_t)(b0 + ln15) * OUT_D + nt * 16 + 4 * lg) = acc;
    }
}

extern "C" void kernel_launch(void* const* d_in, const int* in_sizes, int n_in,
                              void* d_out, int out_size, void* d_ws, size_t ws_size,
                              hipStream_t stream) {
    const float* x    = (const float*)d_in[0];
    const float* h0   = (const float*)d_in[1];
    const float* W_ih = (const float*)d_in[2];
    const float* b_ih = (const float*)d_in[3];
    const float* W_hh = (const float*)d_in[4];
    const float* b_hh = (const float*)d_in[5];
    const float* W_ho = (const float*)d_in[6];
    const float* b_ho = (const float*)d_in[7];
    rnn_fused<<<B_TOT / BM, 512, 0, stream>>>(x, h0, W_ih, b_ih, W_hh, b_hh,
                                              W_ho, b_ho, (float*)d_out);
}